// Round 8
// baseline (162.919 us; speedup 1.0000x reference)
//
#include <hip/hip_runtime.h>
#include <hip/hip_bf16.h>

#define NSP 4096
#define BEPS 1e-5f
#define JSPLIT 4
#define JCHUNK (NSP / JSPLIT)

using short8  = __attribute__((ext_vector_type(8))) short;
using half8   = __attribute__((ext_vector_type(8))) _Float16;
using f32x4   = __attribute__((ext_vector_type(4))) float;
using f32x16  = __attribute__((ext_vector_type(16))) float;

// scale * log2(e) : softmax exp(s*scale) == exp2(s*SCALE_LOG2E)
// log2(e)/sqrt(32) = 1.4426950408889634 / 5.656854249492381
#define SCALE_LOG2E 0.2550348883f

__device__ __forceinline__ float b2f(unsigned short u) {
  return __uint_as_float(((unsigned)u) << 16);
}
__device__ __forceinline__ float b2f_lo(unsigned w) {
  return __uint_as_float(w << 16);
}
__device__ __forceinline__ float b2f_hi(unsigned w) {
  return __uint_as_float(w & 0xffff0000u);
}
// float -> bf16 bits, round-nearest-even (manual; non-hot paths)
__device__ __forceinline__ unsigned short f2b(float x) {
  unsigned u = __float_as_uint(x);
  u += 0x7fffu + ((u >> 16) & 1u);
  return (unsigned short)(u >> 16);
}
__device__ __forceinline__ unsigned pk_bf16(float a, float b) {
  return ((unsigned)f2b(b) << 16) | (unsigned)f2b(a);
}
// HW packed convert: v_cvt_pk_bf16_f32 on gfx950 (1 inst vs ~10 manual)
__device__ __forceinline__ unsigned pk2u(float a, float b) {
  __hip_bfloat162 h = __float22bfloat162_rn(float2{a, b});
  unsigned r;
  __builtin_memcpy(&r, &h, sizeof(r));
  return r;
}
// float -> fp16 bits (RNE via v_cvt_f16_f32)
__device__ __forceinline__ unsigned short f2h(float x) {
  _Float16 h = (_Float16)x;
  unsigned short u;
  __builtin_memcpy(&u, &h, sizeof(u));
  return u;
}
__device__ __forceinline__ unsigned pk_h2(float a, float b) {
  return ((unsigned)f2h(b) << 16) | (unsigned)f2h(a);
}

// ---------------- Kernel 0: transpose-cast x -> xT (b, n, c) fp16; z==2 casts weights --
__global__ __launch_bounds__(256) void transpose_x_kernel(
    const float* __restrict__ x, unsigned short* __restrict__ xT,
    const float* __restrict__ qkv_w, const float* __restrict__ proj_w,
    unsigned short* __restrict__ wqb, unsigned short* __restrict__ wpb)
{
  const int t = threadIdx.x;
  if (blockIdx.z == 2) {   // weight cast lane: 256 blocks x 256 thr, 3 elems each
    const int tid = (blockIdx.x * 4 + blockIdx.y) * 256 + t;   // 0..65535
    #pragma unroll
    for (int u = 0; u < 3; ++u) {
      const int i = tid + u * 65536;
      if (i < 131072)  wqb[i] = f2h(qkv_w[i]);
      else             wpb[i - 131072] = f2b(proj_w[i - 131072]);
    }
    return;
  }
  const int n0 = blockIdx.x * 64, c0 = blockIdx.y * 64, b = blockIdx.z;
  __shared__ __align__(16) unsigned short tx[64][72];   // [n][c]
  const int row = t >> 2;        // c index within tile
  const int seg = t & 3;         // 16 n each
  {
    const float* xp = x + ((size_t)(b * 256 + c0 + row)) * NSP + n0 + seg * 16;
    #pragma unroll
    for (int q4 = 0; q4 < 4; ++q4) {
      const float4 a = *reinterpret_cast<const float4*>(xp + q4 * 4);
      tx[seg * 16 + q4 * 4 + 0][row] = f2h(a.x);
      tx[seg * 16 + q4 * 4 + 1][row] = f2h(a.y);
      tx[seg * 16 + q4 * 4 + 2][row] = f2h(a.z);
      tx[seg * 16 + q4 * 4 + 3][row] = f2h(a.w);
    }
  }
  __syncthreads();
  const int nrow = t >> 2, ch = t & 3;
  unsigned short* op = xT + ((size_t)(b * NSP + n0 + nrow)) * 256 + c0 + ch * 16;
  *reinterpret_cast<float4*>(op)     = *reinterpret_cast<const float4*>(&tx[nrow][ch * 16]);
  *reinterpret_cast<float4*>(op + 8) = *reinterpret_cast<const float4*>(&tx[nrow][ch * 16 + 8]);
}

// ---------------- Kernel 1: MFMA qkv GEMM (fp16) + BN + scatter (128-n tiles) ----------
// r4-verified structure (kc-loop staging; r6's reg-prefetch regressed — reverted).
__global__ __launch_bounds__(256) void qkv_gemm_kernel(
    const unsigned short* __restrict__ xT, const unsigned short* __restrict__ wqb,
    const float* __restrict__ gg, const float* __restrict__ bb,
    const float* __restrict__ mm, const float* __restrict__ vv,
    unsigned short* __restrict__ qb, unsigned short* __restrict__ kb,
    unsigned short* __restrict__ vb)
{
  const int n0 = blockIdx.x * 128;
  const int cotile = blockIdx.y;           // 8 tiles of 64 co
  const int b = blockIdx.z;
  const int co0 = cotile * 64;
  const int t = threadIdx.x;
  __shared__ __align__(16) unsigned short wt[64][136];    // [co][k-chunk 128] fp16
  __shared__ __align__(16) unsigned short xt[128][136];   // [n][k-chunk 128] fp16
  const int lane = t & 63, wave = t >> 6;
  const int m16 = lane & 15, quad = lane >> 4;

  f32x4 acc[8] = {};
  for (int kc = 0; kc < 2; ++kc) {
    if (kc) __syncthreads();
    {
      const unsigned short* wp = wqb + (size_t)(co0 + (t >> 2)) * 256 + kc * 128 + (t & 3) * 32;
      #pragma unroll
      for (int u = 0; u < 4; ++u)
        *reinterpret_cast<float4*>(&wt[t >> 2][(t & 3) * 32 + u * 8]) =
            *reinterpret_cast<const float4*>(wp + u * 8);
      const unsigned short* xp = xT + ((size_t)(b * NSP + n0 + (t >> 1))) * 256 + kc * 128 + (t & 1) * 64;
      #pragma unroll
      for (int u = 0; u < 8; ++u)
        *reinterpret_cast<float4*>(&xt[t >> 1][(t & 1) * 64 + u * 8]) =
            *reinterpret_cast<const float4*>(xp + u * 8);
    }
    __syncthreads();
    if ((cotile & 1) == 0) {   // q/k: A = W (m=co), B = X (n=spatial)
      #pragma unroll
      for (int ks = 0; ks < 4; ++ks) {
        const half8 af = *reinterpret_cast<const half8*>(&wt[wave * 16 + m16][ks * 32 + quad * 8]);
        #pragma unroll
        for (int nt = 0; nt < 8; ++nt) {
          const half8 bf = *reinterpret_cast<const half8*>(&xt[nt * 16 + m16][ks * 32 + quad * 8]);
          acc[nt] = __builtin_amdgcn_mfma_f32_16x16x32_f16(af, bf, acc[nt], 0, 0, 0);
        }
      }
    } else {                   // v: swapped -> A = X (m=spatial), B = W (n=co)
      #pragma unroll
      for (int ks = 0; ks < 4; ++ks) {
        const half8 bf = *reinterpret_cast<const half8*>(&wt[wave * 16 + m16][ks * 32 + quad * 8]);
        #pragma unroll
        for (int nt = 0; nt < 8; ++nt) {
          const half8 af = *reinterpret_cast<const half8*>(&xt[nt * 16 + m16][ks * 32 + quad * 8]);
          acc[nt] = __builtin_amdgcn_mfma_f32_16x16x32_f16(af, bf, acc[nt], 0, 0, 0);
        }
      }
    }
  }

  const int head = cotile >> 1;
  const int bh = b * 4 + head;
  if ((cotile & 1) == 0) {
    const int coh = wave * 16 + quad * 4;   // 0..63 within head half (q if <32 else k)
    const bool isq = (coh < 32);
    const float fold = isq ? SCALE_LOG2E : 1.0f;   // pre-scale q for softmax exp2
    float sc[4], bi[4];
    #pragma unroll
    for (int r = 0; r < 4; ++r) {
      const int c = co0 + coh + r;
      const float s0 = gg[c] * rsqrtf(vv[c] + BEPS);
      sc[r] = s0 * fold;
      bi[r] = (bb[c] - mm[c] * s0) * fold;
    }
    unsigned short* dst = isq ? qb : kb;
    const int d0 = coh & 31;
    #pragma unroll
    for (int nt = 0; nt < 8; ++nt) {
      const int i = n0 + nt * 16 + m16;
      uint2 pk2;
      pk2.x = pk_h2(acc[nt][0] * sc[0] + bi[0], acc[nt][1] * sc[1] + bi[1]);
      pk2.y = pk_h2(acc[nt][2] * sc[2] + bi[2], acc[nt][3] * sc[3] + bi[3]);
      *reinterpret_cast<uint2*>(dst + ((size_t)bh * NSP + i) * 32 + d0) = pk2;
    }
  } else {
    const int c = co0 + wave * 16 + m16;
    const float sc = gg[c] * rsqrtf(vv[c] + BEPS);
    const float bi = bb[c] - mm[c] * sc;
    const int d = wave * 16 + m16;
    #pragma unroll
    for (int nt = 0; nt < 8; ++nt) {
      const int j = n0 + nt * 16 + quad * 4;
      uint2 pk2;
      pk2.x = pk_bf16(acc[nt][0] * sc + bi, acc[nt][1] * sc + bi);
      pk2.y = pk_bf16(acc[nt][2] * sc + bi, acc[nt][3] * sc + bi);
      *reinterpret_cast<uint2*>(vb + ((size_t)(bh * 64 + d)) * NSP + j) = pk2;
    }
  }
}

// ---------------- Kernel 2: MFMA flash attention, 32x32 MFMA, exchange-free PV ---------
// (r4-verified structure: single K/V buffer, 2 barriers/tile.)
// Q pre-scaled by scale*log2e (qkv epilogue) -> softmax is exp2(s) directly.
// 32x32x16 S-MFMA (A=K m=j, B=Q n=i): lane holds P[i=lane&31][j = (r&3)+8*(r>>2)+4*hi].
// EXCHANGE-FREE PV: A-frag = lane's own pk words; V j-columns pre-permuted in LDS
// (q0,q2,q1,q3 within each 16-j block) so Σ_j P[j]V[j] is unchanged.
// REG BUDGET: kernel uses 96 unified regs (64 VGPR + 32 AGPR).
// (256,5) -> 102-reg budget >= 96 needed: no spill, and IF the HW granule is fine
// enough, 5 waves/SIMD = 20 waves/CU (+25% over (256,4)'s 16). r3 lesson still holds:
// (256,8) -> 64 budget -> spill storm. A null here = HW granule rounds 96->128.
__global__ __launch_bounds__(256, 5) void attn_kernel(
    const unsigned short* __restrict__ qb, const unsigned short* __restrict__ kb,
    const unsigned short* __restrict__ vb,
    unsigned short* __restrict__ Opart, float* __restrict__ lpart)
{
  const int i0    = blockIdx.x * 128;
  const int bh    = blockIdx.y;
  const int split = blockIdx.z;
  const int jbase = split * JCHUNK;
  const int t  = threadIdx.x;
  const int lane = t & 63, wave = t >> 6;
  const int l31 = lane & 31, hi = lane >> 5;

  // 14336 B total; qs (10240 B) overlays ks+vs (5120 + 9216 B)
  __shared__ __align__(16) unsigned short smem[7168];
  unsigned short (*qs)[40] = (unsigned short(*)[40])smem;          // [i][d] fp16
  unsigned short (*ks)[40] = (unsigned short(*)[40])smem;          // [j][d] fp16
  unsigned short (*vs)[72] = (unsigned short(*)[72])(smem + 2560); // [d][j-permuted] bf16

  {  // stage Q once: 128 rows x 32 fp16 (each thread 32B)
    const unsigned short* qp = qb + ((size_t)bh * NSP + i0) * 32;
    const int r = t >> 1, h = t & 1;
    *reinterpret_cast<float4*>(&qs[r][h * 16]) =
        *reinterpret_cast<const float4*>(qp + r * 32 + h * 16);
    *reinterpret_cast<float4*>(&qs[r][h * 16 + 8]) =
        *reinterpret_cast<const float4*>(qp + r * 32 + h * 16 + 8);
  }

  const int srow = t >> 2, schunk = t & 3;
  const unsigned short* kbase = kb + (size_t)bh * NSP * 32;
  const unsigned short* vbase = vb + (size_t)bh * 64 * NSP;

  // prologue: tile 0 -> regs (overlaps Q staging latency)
  float4 kreg, vreg0, vreg1;
  kreg  = *reinterpret_cast<const float4*>(kbase + (size_t)(jbase + srow) * 32 + schunk * 8);
  vreg0 = *reinterpret_cast<const float4*>(vbase + (size_t)srow * NSP + jbase + schunk * 16);
  vreg1 = *reinterpret_cast<const float4*>(vbase + (size_t)srow * NSP + jbase + schunk * 16 + 8);

  __syncthreads();   // Q visible
  // Q B-frags: B[k=d][col=i]: lane reads Q[wave*32 + l31][kt*16 + hi*8 ..+7]
  half8 qfrag[2];
  qfrag[0] = *reinterpret_cast<const half8*>(&qs[wave * 32 + l31][hi * 8]);
  qfrag[1] = *reinterpret_cast<const half8*>(&qs[wave * 32 + l31][16 + hi * 8]);
  __syncthreads();   // all qfrag reads done before ks/vs overwrite qs

  // commit tile 0 to LDS; V columns quad-permuted (q0,q2,q1,q3 within each 16-j block)
  *reinterpret_cast<float4*>(&ks[srow][schunk * 8]) = kreg;
  {
    uint2* vd = reinterpret_cast<uint2*>(&vs[srow][schunk * 16]);
    const uint2* v0 = reinterpret_cast<const uint2*>(&vreg0);
    const uint2* v1 = reinterpret_cast<const uint2*>(&vreg1);
    vd[0] = v0[0];   // pos 0-3  <- j 0-3   (q0)
    vd[1] = v1[0];   // pos 4-7  <- j 8-11  (q2)
    vd[2] = v0[1];   // pos 8-11 <- j 4-7   (q1)
    vd[3] = v1[1];   // pos12-15 <- j 12-15 (q3)
  }
  __syncthreads();   // tile 0 visible

  float rsum = 0.f;
  f32x16 oacc[2] = {};   // [dt] : O[i-runs][d = dt*32 + l31]

  for (int jt0 = 0; jt0 < JCHUNK; jt0 += 64) {
    const bool more = (jt0 + 64) < JCHUNK;
    if (more) {   // prefetch tile j+1 into regs; latency overlaps compute below
      const int jn = jbase + jt0 + 64;
      kreg  = *reinterpret_cast<const float4*>(kbase + (size_t)(jn + srow) * 32 + schunk * 8);
      vreg0 = *reinterpret_cast<const float4*>(vbase + (size_t)srow * NSP + jn + schunk * 16);
      vreg1 = *reinterpret_cast<const float4*>(vbase + (size_t)srow * NSP + jn + schunk * 16 + 8);
    }

    // K A-frags: A[row=j][k=d]: lane reads K[jt32*32 + l31][kt*16 + hi*8 ..+7]
    half8 kf[2][2];
    #pragma unroll
    for (int jt32 = 0; jt32 < 2; ++jt32) {
      kf[jt32][0] = *reinterpret_cast<const half8*>(&ks[jt32 * 32 + l31][hi * 8]);
      kf[jt32][1] = *reinterpret_cast<const half8*>(&ks[jt32 * 32 + l31][16 + hi * 8]);
    }

    #pragma unroll
    for (int jt32 = 0; jt32 < 2; ++jt32) {
      // S tile: C[row=j][col=i], j = (r&3)+8*(r>>2)+4*hi + jt32*32, i = l31 (+wave*32)
      f32x16 sacc = {};
      sacc = __builtin_amdgcn_mfma_f32_32x32x16_f16(kf[jt32][0], qfrag[0], sacc, 0, 0, 0);
      sacc = __builtin_amdgcn_mfma_f32_32x32x16_f16(kf[jt32][1], qfrag[1], sacc, 0, 0, 0);

      // softmax numerator: exp2 (q pre-scaled), accumulate row-sum, pack to bf16 pairs
      unsigned pk[8];
      #pragma unroll
      for (int c = 0; c < 8; ++c) {
        const float p0 = __builtin_amdgcn_exp2f(sacc[2 * c]);
        const float p1 = __builtin_amdgcn_exp2f(sacc[2 * c + 1]);
        rsum += p0 + p1;
        pk[c] = pk2u(p0, p1);   // pair (j, j+1) within a 4-run
      }

      // PV: A-frag = own pk words (no cross-lane exchange; V columns pre-permuted).
      #pragma unroll
      for (int kt = 0; kt < 2; ++kt) {
        uint4 aw;
        aw.x = pk[4 * kt + 0];
        aw.y = pk[4 * kt + 1];
        aw.z = pk[4 * kt + 2];
        aw.w = pk[4 * kt + 3];
        short8 af;
        __builtin_memcpy(&af, &aw, 16);
        #pragma unroll
        for (int dt = 0; dt < 2; ++dt) {
          const short8 vf = *reinterpret_cast<const short8*>(
              &vs[dt * 32 + l31][jt32 * 32 + kt * 16 + hi * 8]);
          oacc[dt] = __builtin_amdgcn_mfma_f32_32x32x16_bf16(af, vf, oacc[dt], 0, 0, 0);
        }
      }
    }

    if (more) {   // commit prefetched tile to LDS
      __syncthreads();   // all reads of ks/vs for tile j done
      *reinterpret_cast<float4*>(&ks[srow][schunk * 8]) = kreg;
      uint2* vd = reinterpret_cast<uint2*>(&vs[srow][schunk * 16]);
      const uint2* v0 = reinterpret_cast<const uint2*>(&vreg0);
      const uint2* v1 = reinterpret_cast<const uint2*>(&vreg1);
      vd[0] = v0[0];
      vd[1] = v1[0];
      vd[2] = v0[1];
      vd[3] = v1[1];
      __syncthreads();   // tile j+1 visible
    }
  }

  // finalize l for this block's j-range: lane and lane^32 hold complementary j-subsets
  {
    float rs = rsum;
    rs += __shfl_xor(rs, 32);
    if (hi == 0)
      lpart[((size_t)split * 8 + bh) * NSP + i0 + wave * 32 + l31] = rs;
  }

  // store unnormalized O partial as bf16: [split][bh][d][i]
  // reg r -> i = (r&3) + 8*(r>>2) + 4*hi  (runs of 4, pack pairs -> uint2 per run)
  #pragma unroll
  for (int dt = 0; dt < 2; ++dt) {
    const int d = dt * 32 + l31;
    #pragma unroll
    for (int R = 0; R < 4; ++R) {
      uint2 pk2;
      pk2.x = pk2u(oacc[dt][4 * R + 0], oacc[dt][4 * R + 1]);
      pk2.y = pk2u(oacc[dt][4 * R + 2], oacc[dt][4 * R + 3]);
      *reinterpret_cast<uint2*>(Opart +
          (((size_t)split * 8 + bh) * 64 + d) * NSP + i0 + wave * 32 + 8 * R + 4 * hi) = pk2;
    }
  }
}

// ---------------- Kernel 3: fused combine + pe -> yT (b, n, c) bf16 (r4-exact) ---------
// (r7's px-split was neutral-to-negative -> reverted to the verified r4 version.)
__global__ __launch_bounds__(256) void fuse_kernel(
    const unsigned short* __restrict__ Opart, const float* __restrict__ lpart,
    const unsigned short* __restrict__ vb,
    const float* __restrict__ pw, const float* __restrict__ pg,
    const float* __restrict__ pb, const float* __restrict__ pm,
    const float* __restrict__ pv,
    unsigned short* __restrict__ yT)
{
  const int py = blockIdx.x;       // spatial row
  const int bh = blockIdx.y;       // 8
  const int b = bh >> 2, h = bh & 3;
  const int t = threadIdx.x;
  const int d = t >> 2, seg = t & 3;      // d 0..63 ; px window = seg*16..+15
  __shared__ float lsum[64];              // stores RECIPROCAL of row-sum
  __shared__ __align__(16) unsigned short yt[64][72];   // [px][d]

  if (t < 64) {
    float ls = 0.f;
    #pragma unroll
    for (int s = 0; s < JSPLIT; ++s)
      ls += lpart[((size_t)s * 8 + bh) * NSP + py * 64 + t];
    lsum[t] = 1.0f / ls;
  }
  __syncthreads();

  const int c = h * 64 + d;
  const int i0 = py * 64 + seg * 16;
  float os[16] = {};
  #pragma unroll
  for (int s = 0; s < JSPLIT; ++s) {
    const uint4* op = reinterpret_cast<const uint4*>(
        Opart + (((size_t)s * 8 + bh) * 64 + d) * NSP + i0);
    const uint4 a = op[0], e = op[1];
    os[0]  += b2f_lo(a.x); os[1]  += b2f_hi(a.x);
    os[2]  += b2f_lo(a.y); os[3]  += b2f_hi(a.y);
    os[4]  += b2f_lo(a.z); os[5]  += b2f_hi(a.z);
    os[6]  += b2f_lo(a.w); os[7]  += b2f_hi(a.w);
    os[8]  += b2f_lo(e.x); os[9]  += b2f_hi(e.x);
    os[10] += b2f_lo(e.y); os[11] += b2f_hi(e.y);
    os[12] += b2f_lo(e.z); os[13] += b2f_hi(e.z);
    os[14] += b2f_lo(e.w); os[15] += b2f_hi(e.w);
  }

  float w9[9];
  #pragma unroll
  for (int i = 0; i < 9; ++i) w9[i] = pw[c * 9 + i];
  const float sc = pg[c] * rsqrtf(pv[c] + BEPS);
  const float bi = pb[c] - pm[c] * sc;
  const unsigned short* vrow = vb + ((size_t)(bh * 64 + d)) * NSP;

  float conv[16] = {};
  #pragma unroll
  for (int dy = -1; dy <= 1; ++dy) {
    const int yy = py + dy;
    if (yy < 0 || yy > 63) continue;
    const unsigned short* vr = vrow + yy * 64 + seg * 16;
    float vals[18];
    const uint4 m0 = *reinterpret_cast<const uint4*>(vr);
    const uint4 m1 = *reinterpret_cast<const uint4*>(vr + 8);
    vals[1]  = b2f_lo(m0.x); vals[2]  = b2f_hi(m0.x);
    vals[3]  = b2f_lo(m0.y); vals[4]  = b2f_hi(m0.y);
    vals[5]  = b2f_lo(m0.z); vals[6]  = b2f_hi(m0.z);
    vals[7]  = b2f_lo(m0.w); vals[8]  = b2f_hi(m0.w);
    vals[9]  = b2f_lo(m1.x); vals[10] = b2f_hi(m1.x);
    vals[11] = b2f_lo(m1.y); vals[12] = b2f_hi(m1.y);
    vals[13] = b2f_lo(m1.z); vals[14] = b2f_hi(m1.z);
    vals[15] = b2f_lo(m1.w); vals[16] = b2f_hi(m1.w);
    vals[0]  = (seg > 0) ? b2f_hi(*reinterpret_cast<const unsigned*>(vr - 2)) : 0.f;
    vals[17] = (seg < 3) ? b2f_lo(*reinterpret_cast<const unsigned*>(vr + 16)) : 0.f;
    const float wr0 = w9[(dy + 1) * 3 + 0], wr1 = w9[(dy + 1) * 3 + 1], wr2 = w9[(dy + 1) * 3 + 2];
    #pragma unroll
    for (int u = 0; u < 16; ++u)
      conv[u] += vals[u] * wr0 + vals[u + 1] * wr1 + vals[u + 2] * wr2;
  }

  #pragma unroll
  for (int u = 0; u < 16; ++u) {
    const float yv = os[u] * lsum[seg * 16 + u] + conv[u] * sc + bi;
    yt[seg * 16 + u][d] = f2b(yv);
  }
  __syncthreads();

  const int prow = t >> 2, ch = t & 3;
  unsigned short* op = yT + ((size_t)(b * NSP + py * 64 + prow)) * 256 + h * 64 + ch * 16;
  *reinterpret_cast<float4*>(op)     = *reinterpret_cast<const float4*>(&yt[prow][ch * 16]);
  *reinterpret_cast<float4*>(op + 8) = *reinterpret_cast<const float4*>(&yt[prow][ch * 16 + 8]);
}

// ---------------- Kernel 4: MFMA proj GEMM + BN -> out f32 (64-n tiles) -----------------
// r4-verified structure (kc-loop staging).
__global__ __launch_bounds__(256) void proj_gemm_kernel(
    const unsigned short* __restrict__ yT, const unsigned short* __restrict__ wpb,
    const float* __restrict__ gg, const float* __restrict__ bb,
    const float* __restrict__ mm, const float* __restrict__ vv,
    float* __restrict__ out)
{
  const int n0 = blockIdx.x * 64;
  const int co0 = blockIdx.y * 64;   // 4 tiles
  const int b = blockIdx.z;
  const int t = threadIdx.x;
  __shared__ __align__(16) unsigned short wt[64][136];
  __shared__ __align__(16) unsigned short yt[64][136];
  const int lane = t & 63, wave = t >> 6;
  const int m16 = lane & 15, quad = lane >> 4;

  f32x4 acc[4] = {};
  for (int kc = 0; kc < 2; ++kc) {
    if (kc) __syncthreads();
    {
      const unsigned short* wp = wpb + (size_t)(co0 + (t >> 2)) * 256 + kc * 128 + (t & 3) * 32;
      #pragma unroll
      for (int u = 0; u < 4; ++u)
        *reinterpret_cast<float4*>(&wt[t >> 2][(t & 3) * 32 + u * 8]) =
            *reinterpret_cast<const float4*>(wp + u * 8);
      const unsigned short* yp = yT + ((size_t)(b * NSP + n0 + (t >> 2))) * 256 + kc * 128 + (t & 3) * 32;
      #pragma unroll
      for (int u = 0; u < 4; ++u)
        *reinterpret_cast<float4*>(&yt[t >> 2][(t & 3) * 32 + u * 8]) =
            *reinterpret_cast<const float4*>(yp + u * 8);
    }
    __syncthreads();
    #pragma unroll
    for (int ks = 0; ks < 4; ++ks) {
      const short8 bf = *reinterpret_cast<const short8*>(&wt[wave * 16 + m16][ks * 32 + quad * 8]);
      #pragma unroll
      for (int nt = 0; nt < 4; ++nt) {
        const short8 af = *reinterpret_cast<const short8*>(&yt[nt * 16 + m16][ks * 32 + quad * 8]);
        acc[nt] = __builtin_amdgcn_mfma_f32_16x16x32_bf16(af, bf, acc[nt], 0, 0, 0);
      }
    }
  }

  const int c = co0 + wave * 16 + m16;
  const float sc = gg[c] * rsqrtf(vv[c] + BEPS);
  const float bi = bb[c] - mm[c] * sc;
  #pragma unroll
  for (int nt = 0; nt < 4; ++nt) {
    const int n = n0 + nt * 16 + quad * 4;
    float4 ov;
    ov.x = acc[nt][0] * sc + bi; ov.y = acc[nt][1] * sc + bi;
    ov.z = acc[nt][2] * sc + bi; ov.w = acc[nt][3] * sc + bi;
    *reinterpret_cast<float4*>(out + ((size_t)(b * 256 + c)) * NSP + n) = ov;
  }
}

extern "C" void kernel_launch(void* const* d_in, const int* in_sizes, int n_in,
                              void* d_out, int out_size, void* d_ws, size_t ws_size,
                              hipStream_t stream)
{
  const float* x      = (const float*)d_in[0];
  const float* qkv_w  = (const float*)d_in[1];
  const float* qkv_g  = (const float*)d_in[2];
  const float* qkv_b  = (const float*)d_in[3];
  const float* qkv_m  = (const float*)d_in[4];
  const float* qkv_v  = (const float*)d_in[5];
  const float* proj_w = (const float*)d_in[6];
  const float* proj_g = (const float*)d_in[7];
  const float* proj_b = (const float*)d_in[8];
  const float* proj_m = (const float*)d_in[9];
  const float* proj_v = (const float*)d_in[10];
  const float* pe_w   = (const float*)d_in[11];
  const float* pe_g   = (const float*)d_in[12];
  const float* pe_b   = (const float*)d_in[13];
  const float* pe_m   = (const float*)d_in[14];
  const float* pe_v   = (const float*)d_in[15];
  float* out = (float*)d_out;

  unsigned short* qb = (unsigned short*)d_ws;             // 2MB (fp16)
  unsigned short* kb = qb + (size_t)8 * NSP * 32;         // 2MB (fp16)
  unsigned short* vb = kb + (size_t)8 * NSP * 32;         // 4MB (bf16)
  unsigned short* Opart = vb + (size_t)8 * 64 * NSP;      // 16MB (bf16)
  float* lpart = (float*)(Opart + (size_t)JSPLIT * 8 * 64 * NSP);  // 512KB
  unsigned short* xT = (unsigned short*)(lpart + (size_t)JSPLIT * 8 * NSP);  // 4MB (fp16)
  unsigned short* yT = xT + (size_t)2 * NSP * 256;        // 4MB (bf16)
  unsigned short* wqb = yT + (size_t)2 * NSP * 256;       // 256KB (fp16)
  unsigned short* wpb = wqb + (size_t)512 * 256;          // 128KB (bf16)

  transpose_x_kernel<<<dim3(64, 4, 3), 256, 0, stream>>>(x, xT, qkv_w, proj_w, wqb, wpb);
  qkv_gemm_kernel<<<dim3(32, 8, 2), 256, 0, stream>>>(xT, wqb, qkv_g, qkv_b, qkv_m, qkv_v,
                                                      qb, kb, vb);
  attn_kernel<<<dim3(32, 8, JSPLIT), 256, 0, stream>>>(qb, kb, vb, Opart, lpart);
  fuse_kernel<<<dim3(64, 8), 256, 0, stream>>>(Opart, lpart, vb,
                                               pe_w, pe_g, pe_b, pe_m, pe_v, yT);
  proj_gemm_kernel<<<dim3(64, 4, 2), 256, 0, stream>>>(yT, wpb, proj_g, proj_b, proj_m, proj_v,
                                                       out);
}

// Round 9
// 154.605 us; speedup vs baseline: 1.0538x; 1.0538x over previous
//
#include <hip/hip_runtime.h>
#include <hip/hip_bf16.h>

#define NSP 4096
#define BEPS 1e-5f
#define JSPLIT 4
#define JCHUNK (NSP / JSPLIT)

using short8  = __attribute__((ext_vector_type(8))) short;
using half8   = __attribute__((ext_vector_type(8))) _Float16;
using f32x4   = __attribute__((ext_vector_type(4))) float;
using f32x16  = __attribute__((ext_vector_type(16))) float;

// scale * log2(e) : softmax exp(s*scale) == exp2(s*SCALE_LOG2E)
// log2(e)/sqrt(32) = 1.4426950408889634 / 5.656854249492381
#define SCALE_LOG2E 0.2550348883f

__device__ __forceinline__ float b2f(unsigned short u) {
  return __uint_as_float(((unsigned)u) << 16);
}
__device__ __forceinline__ float b2f_lo(unsigned w) {
  return __uint_as_float(w << 16);
}
__device__ __forceinline__ float b2f_hi(unsigned w) {
  return __uint_as_float(w & 0xffff0000u);
}
// float -> bf16 bits, round-nearest-even (manual; non-hot paths)
__device__ __forceinline__ unsigned short f2b(float x) {
  unsigned u = __float_as_uint(x);
  u += 0x7fffu + ((u >> 16) & 1u);
  return (unsigned short)(u >> 16);
}
__device__ __forceinline__ unsigned pk_bf16(float a, float b) {
  return ((unsigned)f2b(b) << 16) | (unsigned)f2b(a);
}
// HW packed convert: v_cvt_pk_bf16_f32 on gfx950 (1 inst vs ~10 manual)
__device__ __forceinline__ unsigned pk2u(float a, float b) {
  __hip_bfloat162 h = __float22bfloat162_rn(float2{a, b});
  unsigned r;
  __builtin_memcpy(&r, &h, sizeof(r));
  return r;
}
// float -> fp16 bits (RNE via v_cvt_f16_f32)
__device__ __forceinline__ unsigned short f2h(float x) {
  _Float16 h = (_Float16)x;
  unsigned short u;
  __builtin_memcpy(&u, &h, sizeof(u));
  return u;
}
__device__ __forceinline__ unsigned pk_h2(float a, float b) {
  return ((unsigned)f2h(b) << 16) | (unsigned)f2h(a);
}

// ---------------- Kernel 0: transpose-cast x -> xT (b, n, c) fp16 ----------------------
// (weight-cast branch removed: qkv/proj now cast weights during their own LDS staging,
// killing the wqb/wpb global round-trip and the qkv->cast scheduling dependency)
__global__ __launch_bounds__(256) void transpose_x_kernel(
    const float* __restrict__ x, unsigned short* __restrict__ xT)
{
  const int t = threadIdx.x;
  const int n0 = blockIdx.x * 64, c0 = blockIdx.y * 64, b = blockIdx.z;
  __shared__ __align__(16) unsigned short tx[64][72];   // [n][c]
  const int row = t >> 2;        // c index within tile
  const int seg = t & 3;         // 16 n each
  {
    const float* xp = x + ((size_t)(b * 256 + c0 + row)) * NSP + n0 + seg * 16;
    #pragma unroll
    for (int q4 = 0; q4 < 4; ++q4) {
      const float4 a = *reinterpret_cast<const float4*>(xp + q4 * 4);
      tx[seg * 16 + q4 * 4 + 0][row] = f2h(a.x);
      tx[seg * 16 + q4 * 4 + 1][row] = f2h(a.y);
      tx[seg * 16 + q4 * 4 + 2][row] = f2h(a.z);
      tx[seg * 16 + q4 * 4 + 3][row] = f2h(a.w);
    }
  }
  __syncthreads();
  const int nrow = t >> 2, ch = t & 3;
  unsigned short* op = xT + ((size_t)(b * NSP + n0 + nrow)) * 256 + c0 + ch * 16;
  *reinterpret_cast<float4*>(op)     = *reinterpret_cast<const float4*>(&tx[nrow][ch * 16]);
  *reinterpret_cast<float4*>(op + 8) = *reinterpret_cast<const float4*>(&tx[nrow][ch * 16 + 8]);
}

// ---------------- Kernel 1: MFMA qkv GEMM (fp16) + BN + scatter (128-n tiles) ----------
// r4-verified structure. Weight cast (f32 -> fp16, pk_h2 RNE) folded into wt staging:
// weights are L2-hot (512 KB), so the f32 re-read is free; saves the wqb round-trip.
__global__ __launch_bounds__(256) void qkv_gemm_kernel(
    const unsigned short* __restrict__ xT, const float* __restrict__ qkv_w,
    const float* __restrict__ gg, const float* __restrict__ bb,
    const float* __restrict__ mm, const float* __restrict__ vv,
    unsigned short* __restrict__ qb, unsigned short* __restrict__ kb,
    unsigned short* __restrict__ vb)
{
  const int n0 = blockIdx.x * 128;
  const int cotile = blockIdx.y;           // 8 tiles of 64 co
  const int b = blockIdx.z;
  const int co0 = cotile * 64;
  const int t = threadIdx.x;
  __shared__ __align__(16) unsigned short wt[64][136];    // [co][k-chunk 128] fp16
  __shared__ __align__(16) unsigned short xt[128][136];   // [n][k-chunk 128] fp16
  const int lane = t & 63, wave = t >> 6;
  const int m16 = lane & 15, quad = lane >> 4;

  f32x4 acc[8] = {};
  for (int kc = 0; kc < 2; ++kc) {
    if (kc) __syncthreads();
    {
      const float* wp = qkv_w + (size_t)(co0 + (t >> 2)) * 256 + kc * 128 + (t & 3) * 32;
      #pragma unroll
      for (int u = 0; u < 4; ++u) {
        const float4 a0 = *reinterpret_cast<const float4*>(wp + u * 8);
        const float4 a1 = *reinterpret_cast<const float4*>(wp + u * 8 + 4);
        uint4 pw4;
        pw4.x = pk_h2(a0.x, a0.y);
        pw4.y = pk_h2(a0.z, a0.w);
        pw4.z = pk_h2(a1.x, a1.y);
        pw4.w = pk_h2(a1.z, a1.w);
        *reinterpret_cast<uint4*>(&wt[t >> 2][(t & 3) * 32 + u * 8]) = pw4;
      }
      const unsigned short* xp = xT + ((size_t)(b * NSP + n0 + (t >> 1))) * 256 + kc * 128 + (t & 1) * 64;
      #pragma unroll
      for (int u = 0; u < 8; ++u)
        *reinterpret_cast<float4*>(&xt[t >> 1][(t & 1) * 64 + u * 8]) =
            *reinterpret_cast<const float4*>(xp + u * 8);
    }
    __syncthreads();
    if ((cotile & 1) == 0) {   // q/k: A = W (m=co), B = X (n=spatial)
      #pragma unroll
      for (int ks = 0; ks < 4; ++ks) {
        const half8 af = *reinterpret_cast<const half8*>(&wt[wave * 16 + m16][ks * 32 + quad * 8]);
        #pragma unroll
        for (int nt = 0; nt < 8; ++nt) {
          const half8 bf = *reinterpret_cast<const half8*>(&xt[nt * 16 + m16][ks * 32 + quad * 8]);
          acc[nt] = __builtin_amdgcn_mfma_f32_16x16x32_f16(af, bf, acc[nt], 0, 0, 0);
        }
      }
    } else {                   // v: swapped -> A = X (m=spatial), B = W (n=co)
      #pragma unroll
      for (int ks = 0; ks < 4; ++ks) {
        const half8 bf = *reinterpret_cast<const half8*>(&wt[wave * 16 + m16][ks * 32 + quad * 8]);
        #pragma unroll
        for (int nt = 0; nt < 8; ++nt) {
          const half8 af = *reinterpret_cast<const half8*>(&xt[nt * 16 + m16][ks * 32 + quad * 8]);
          acc[nt] = __builtin_amdgcn_mfma_f32_16x16x32_f16(af, bf, acc[nt], 0, 0, 0);
        }
      }
    }
  }

  const int head = cotile >> 1;
  const int bh = b * 4 + head;
  if ((cotile & 1) == 0) {
    const int coh = wave * 16 + quad * 4;   // 0..63 within head half (q if <32 else k)
    const bool isq = (coh < 32);
    const float fold = isq ? SCALE_LOG2E : 1.0f;   // pre-scale q for softmax exp2
    float sc[4], bi[4];
    #pragma unroll
    for (int r = 0; r < 4; ++r) {
      const int c = co0 + coh + r;
      const float s0 = gg[c] * rsqrtf(vv[c] + BEPS);
      sc[r] = s0 * fold;
      bi[r] = (bb[c] - mm[c] * s0) * fold;
    }
    unsigned short* dst = isq ? qb : kb;
    const int d0 = coh & 31;
    #pragma unroll
    for (int nt = 0; nt < 8; ++nt) {
      const int i = n0 + nt * 16 + m16;
      uint2 pk2;
      pk2.x = pk_h2(acc[nt][0] * sc[0] + bi[0], acc[nt][1] * sc[1] + bi[1]);
      pk2.y = pk_h2(acc[nt][2] * sc[2] + bi[2], acc[nt][3] * sc[3] + bi[3]);
      *reinterpret_cast<uint2*>(dst + ((size_t)bh * NSP + i) * 32 + d0) = pk2;
    }
  } else {
    const int c = co0 + wave * 16 + m16;
    const float sc = gg[c] * rsqrtf(vv[c] + BEPS);
    const float bi = bb[c] - mm[c] * sc;
    const int d = wave * 16 + m16;
    #pragma unroll
    for (int nt = 0; nt < 8; ++nt) {
      const int j = n0 + nt * 16 + quad * 4;
      uint2 pk2;
      pk2.x = pk_bf16(acc[nt][0] * sc + bi, acc[nt][1] * sc + bi);
      pk2.y = pk_bf16(acc[nt][2] * sc + bi, acc[nt][3] * sc + bi);
      *reinterpret_cast<uint2*>(vb + ((size_t)(bh * 64 + d)) * NSP + j) = pk2;
    }
  }
}

// ---------------- Kernel 2: MFMA flash attention, 32x32 MFMA, exchange-free PV ---------
// (r4-verified structure: single K/V buffer, 2 barriers/tile, (256,4).)
// Q pre-scaled by scale*log2e (qkv epilogue) -> softmax is exp2(s) directly.
// 32x32x16 S-MFMA (A=K m=j, B=Q n=i): lane holds P[i=lane&31][j = (r&3)+8*(r>>2)+4*hi].
// EXCHANGE-FREE PV: A-frag = lane's own pk words; V j-columns pre-permuted in LDS
// (q0,q2,q1,q3 within each 16-j block) so Σ_j P[j]V[j] is unchanged.
// REG BUDGET (r3+r8 lessons): true unified footprint ~112 regs (64 VGPR + ~48 AGPR
// incl. sacc). (256,4) = 128 budget: fits, no spill — the minimum viable bound.
// (256,5) = 102: compiler squeezed to 48 VGPR + scratch spills (FETCH/WRITE +15 MB
// each, attn 47 -> 53.8 us). (256,8) = 64: spill storm. DO NOT raise waves/EU.
__global__ __launch_bounds__(256, 4) void attn_kernel(
    const unsigned short* __restrict__ qb, const unsigned short* __restrict__ kb,
    const unsigned short* __restrict__ vb,
    unsigned short* __restrict__ Opart, float* __restrict__ lpart)
{
  const int i0    = blockIdx.x * 128;
  const int bh    = blockIdx.y;
  const int split = blockIdx.z;
  const int jbase = split * JCHUNK;
  const int t  = threadIdx.x;
  const int lane = t & 63, wave = t >> 6;
  const int l31 = lane & 31, hi = lane >> 5;

  // 14336 B total; qs (10240 B) overlays ks+vs (5120 + 9216 B)
  __shared__ __align__(16) unsigned short smem[7168];
  unsigned short (*qs)[40] = (unsigned short(*)[40])smem;          // [i][d] fp16
  unsigned short (*ks)[40] = (unsigned short(*)[40])smem;          // [j][d] fp16
  unsigned short (*vs)[72] = (unsigned short(*)[72])(smem + 2560); // [d][j-permuted] bf16

  {  // stage Q once: 128 rows x 32 fp16 (each thread 32B)
    const unsigned short* qp = qb + ((size_t)bh * NSP + i0) * 32;
    const int r = t >> 1, h = t & 1;
    *reinterpret_cast<float4*>(&qs[r][h * 16]) =
        *reinterpret_cast<const float4*>(qp + r * 32 + h * 16);
    *reinterpret_cast<float4*>(&qs[r][h * 16 + 8]) =
        *reinterpret_cast<const float4*>(qp + r * 32 + h * 16 + 8);
  }

  const int srow = t >> 2, schunk = t & 3;
  const unsigned short* kbase = kb + (size_t)bh * NSP * 32;
  const unsigned short* vbase = vb + (size_t)bh * 64 * NSP;

  // prologue: tile 0 -> regs (overlaps Q staging latency)
  float4 kreg, vreg0, vreg1;
  kreg  = *reinterpret_cast<const float4*>(kbase + (size_t)(jbase + srow) * 32 + schunk * 8);
  vreg0 = *reinterpret_cast<const float4*>(vbase + (size_t)srow * NSP + jbase + schunk * 16);
  vreg1 = *reinterpret_cast<const float4*>(vbase + (size_t)srow * NSP + jbase + schunk * 16 + 8);

  __syncthreads();   // Q visible
  // Q B-frags: B[k=d][col=i]: lane reads Q[wave*32 + l31][kt*16 + hi*8 ..+7]
  half8 qfrag[2];
  qfrag[0] = *reinterpret_cast<const half8*>(&qs[wave * 32 + l31][hi * 8]);
  qfrag[1] = *reinterpret_cast<const half8*>(&qs[wave * 32 + l31][16 + hi * 8]);
  __syncthreads();   // all qfrag reads done before ks/vs overwrite qs

  // commit tile 0 to LDS; V columns quad-permuted (q0,q2,q1,q3 within each 16-j block)
  *reinterpret_cast<float4*>(&ks[srow][schunk * 8]) = kreg;
  {
    uint2* vd = reinterpret_cast<uint2*>(&vs[srow][schunk * 16]);
    const uint2* v0 = reinterpret_cast<const uint2*>(&vreg0);
    const uint2* v1 = reinterpret_cast<const uint2*>(&vreg1);
    vd[0] = v0[0];   // pos 0-3  <- j 0-3   (q0)
    vd[1] = v1[0];   // pos 4-7  <- j 8-11  (q2)
    vd[2] = v0[1];   // pos 8-11 <- j 4-7   (q1)
    vd[3] = v1[1];   // pos12-15 <- j 12-15 (q3)
  }
  __syncthreads();   // tile 0 visible

  float rsum = 0.f;
  f32x16 oacc[2] = {};   // [dt] : O[i-runs][d = dt*32 + l31]

  for (int jt0 = 0; jt0 < JCHUNK; jt0 += 64) {
    const bool more = (jt0 + 64) < JCHUNK;
    if (more) {   // prefetch tile j+1 into regs; latency overlaps compute below
      const int jn = jbase + jt0 + 64;
      kreg  = *reinterpret_cast<const float4*>(kbase + (size_t)(jn + srow) * 32 + schunk * 8);
      vreg0 = *reinterpret_cast<const float4*>(vbase + (size_t)srow * NSP + jn + schunk * 16);
      vreg1 = *reinterpret_cast<const float4*>(vbase + (size_t)srow * NSP + jn + schunk * 16 + 8);
    }

    // K A-frags: A[row=j][k=d]: lane reads K[jt32*32 + l31][kt*16 + hi*8 ..+7]
    half8 kf[2][2];
    #pragma unroll
    for (int jt32 = 0; jt32 < 2; ++jt32) {
      kf[jt32][0] = *reinterpret_cast<const half8*>(&ks[jt32 * 32 + l31][hi * 8]);
      kf[jt32][1] = *reinterpret_cast<const half8*>(&ks[jt32 * 32 + l31][16 + hi * 8]);
    }

    #pragma unroll
    for (int jt32 = 0; jt32 < 2; ++jt32) {
      // S tile: C[row=j][col=i], j = (r&3)+8*(r>>2)+4*hi + jt32*32, i = l31 (+wave*32)
      f32x16 sacc = {};
      sacc = __builtin_amdgcn_mfma_f32_32x32x16_f16(kf[jt32][0], qfrag[0], sacc, 0, 0, 0);
      sacc = __builtin_amdgcn_mfma_f32_32x32x16_f16(kf[jt32][1], qfrag[1], sacc, 0, 0, 0);

      // softmax numerator: exp2 (q pre-scaled), accumulate row-sum, pack to bf16 pairs
      unsigned pk[8];
      #pragma unroll
      for (int c = 0; c < 8; ++c) {
        const float p0 = __builtin_amdgcn_exp2f(sacc[2 * c]);
        const float p1 = __builtin_amdgcn_exp2f(sacc[2 * c + 1]);
        rsum += p0 + p1;
        pk[c] = pk2u(p0, p1);   // pair (j, j+1) within a 4-run
      }

      // PV: A-frag = own pk words (no cross-lane exchange; V columns pre-permuted).
      #pragma unroll
      for (int kt = 0; kt < 2; ++kt) {
        uint4 aw;
        aw.x = pk[4 * kt + 0];
        aw.y = pk[4 * kt + 1];
        aw.z = pk[4 * kt + 2];
        aw.w = pk[4 * kt + 3];
        short8 af;
        __builtin_memcpy(&af, &aw, 16);
        #pragma unroll
        for (int dt = 0; dt < 2; ++dt) {
          const short8 vf = *reinterpret_cast<const short8*>(
              &vs[dt * 32 + l31][jt32 * 32 + kt * 16 + hi * 8]);
          oacc[dt] = __builtin_amdgcn_mfma_f32_32x32x16_bf16(af, vf, oacc[dt], 0, 0, 0);
        }
      }
    }

    if (more) {   // commit prefetched tile to LDS
      __syncthreads();   // all reads of ks/vs for tile j done
      *reinterpret_cast<float4*>(&ks[srow][schunk * 8]) = kreg;
      uint2* vd = reinterpret_cast<uint2*>(&vs[srow][schunk * 16]);
      const uint2* v0 = reinterpret_cast<const uint2*>(&vreg0);
      const uint2* v1 = reinterpret_cast<const uint2*>(&vreg1);
      vd[0] = v0[0];
      vd[1] = v1[0];
      vd[2] = v0[1];
      vd[3] = v1[1];
      __syncthreads();   // tile j+1 visible
    }
  }

  // finalize l for this block's j-range: lane and lane^32 hold complementary j-subsets
  {
    float rs = rsum;
    rs += __shfl_xor(rs, 32);
    if (hi == 0)
      lpart[((size_t)split * 8 + bh) * NSP + i0 + wave * 32 + l31] = rs;
  }

  // store unnormalized O partial as bf16: [split][bh][d][i]
  // reg r -> i = (r&3) + 8*(r>>2) + 4*hi  (runs of 4, pack pairs -> uint2 per run)
  #pragma unroll
  for (int dt = 0; dt < 2; ++dt) {
    const int d = dt * 32 + l31;
    #pragma unroll
    for (int R = 0; R < 4; ++R) {
      uint2 pk2;
      pk2.x = pk2u(oacc[dt][4 * R + 0], oacc[dt][4 * R + 1]);
      pk2.y = pk2u(oacc[dt][4 * R + 2], oacc[dt][4 * R + 3]);
      *reinterpret_cast<uint2*>(Opart +
          (((size_t)split * 8 + bh) * 64 + d) * NSP + i0 + wave * 32 + 8 * R + 4 * hi) = pk2;
    }
  }
}

// ---------------- Kernel 3: fused combine + pe -> yT (b, n, c) bf16 (r4-exact) ---------
__global__ __launch_bounds__(256) void fuse_kernel(
    const unsigned short* __restrict__ Opart, const float* __restrict__ lpart,
    const unsigned short* __restrict__ vb,
    const float* __restrict__ pw, const float* __restrict__ pg,
    const float* __restrict__ pb, const float* __restrict__ pm,
    const float* __restrict__ pv,
    unsigned short* __restrict__ yT)
{
  const int py = blockIdx.x;       // spatial row
  const int bh = blockIdx.y;       // 8
  const int b = bh >> 2, h = bh & 3;
  const int t = threadIdx.x;
  const int d = t >> 2, seg = t & 3;      // d 0..63 ; px window = seg*16..+15
  __shared__ float lsum[64];              // stores RECIPROCAL of row-sum
  __shared__ __align__(16) unsigned short yt[64][72];   // [px][d]

  if (t < 64) {
    float ls = 0.f;
    #pragma unroll
    for (int s = 0; s < JSPLIT; ++s)
      ls += lpart[((size_t)s * 8 + bh) * NSP + py * 64 + t];
    lsum[t] = 1.0f / ls;
  }
  __syncthreads();

  const int c = h * 64 + d;
  const int i0 = py * 64 + seg * 16;
  float os[16] = {};
  #pragma unroll
  for (int s = 0; s < JSPLIT; ++s) {
    const uint4* op = reinterpret_cast<const uint4*>(
        Opart + (((size_t)s * 8 + bh) * 64 + d) * NSP + i0);
    const uint4 a = op[0], e = op[1];
    os[0]  += b2f_lo(a.x); os[1]  += b2f_hi(a.x);
    os[2]  += b2f_lo(a.y); os[3]  += b2f_hi(a.y);
    os[4]  += b2f_lo(a.z); os[5]  += b2f_hi(a.z);
    os[6]  += b2f_lo(a.w); os[7]  += b2f_hi(a.w);
    os[8]  += b2f_lo(e.x); os[9]  += b2f_hi(e.x);
    os[10] += b2f_lo(e.y); os[11] += b2f_hi(e.y);
    os[12] += b2f_lo(e.z); os[13] += b2f_hi(e.z);
    os[14] += b2f_lo(e.w); os[15] += b2f_hi(e.w);
  }

  float w9[9];
  #pragma unroll
  for (int i = 0; i < 9; ++i) w9[i] = pw[c * 9 + i];
  const float sc = pg[c] * rsqrtf(pv[c] + BEPS);
  const float bi = pb[c] - pm[c] * sc;
  const unsigned short* vrow = vb + ((size_t)(bh * 64 + d)) * NSP;

  float conv[16] = {};
  #pragma unroll
  for (int dy = -1; dy <= 1; ++dy) {
    const int yy = py + dy;
    if (yy < 0 || yy > 63) continue;
    const unsigned short* vr = vrow + yy * 64 + seg * 16;
    float vals[18];
    const uint4 m0 = *reinterpret_cast<const uint4*>(vr);
    const uint4 m1 = *reinterpret_cast<const uint4*>(vr + 8);
    vals[1]  = b2f_lo(m0.x); vals[2]  = b2f_hi(m0.x);
    vals[3]  = b2f_lo(m0.y); vals[4]  = b2f_hi(m0.y);
    vals[5]  = b2f_lo(m0.z); vals[6]  = b2f_hi(m0.z);
    vals[7]  = b2f_lo(m0.w); vals[8]  = b2f_hi(m0.w);
    vals[9]  = b2f_lo(m1.x); vals[10] = b2f_hi(m1.x);
    vals[11] = b2f_lo(m1.y); vals[12] = b2f_hi(m1.y);
    vals[13] = b2f_lo(m1.z); vals[14] = b2f_hi(m1.z);
    vals[15] = b2f_lo(m1.w); vals[16] = b2f_hi(m1.w);
    vals[0]  = (seg > 0) ? b2f_hi(*reinterpret_cast<const unsigned*>(vr - 2)) : 0.f;
    vals[17] = (seg < 3) ? b2f_lo(*reinterpret_cast<const unsigned*>(vr + 16)) : 0.f;
    const float wr0 = w9[(dy + 1) * 3 + 0], wr1 = w9[(dy + 1) * 3 + 1], wr2 = w9[(dy + 1) * 3 + 2];
    #pragma unroll
    for (int u = 0; u < 16; ++u)
      conv[u] += vals[u] * wr0 + vals[u + 1] * wr1 + vals[u + 2] * wr2;
  }

  #pragma unroll
  for (int u = 0; u < 16; ++u) {
    const float yv = os[u] * lsum[seg * 16 + u] + conv[u] * sc + bi;
    yt[seg * 16 + u][d] = f2b(yv);
  }
  __syncthreads();

  const int prow = t >> 2, ch = t & 3;
  unsigned short* op = yT + ((size_t)(b * NSP + py * 64 + prow)) * 256 + h * 64 + ch * 16;
  *reinterpret_cast<float4*>(op)     = *reinterpret_cast<const float4*>(&yt[prow][ch * 16]);
  *reinterpret_cast<float4*>(op + 8) = *reinterpret_cast<const float4*>(&yt[prow][ch * 16 + 8]);
}

// ---------------- Kernel 4: MFMA proj GEMM + BN -> out f32 (64-n tiles) -----------------
// r4-verified structure. Weight cast (f32 -> bf16, HW pk2u RNE) folded into wt staging.
__global__ __launch_bounds__(256) void proj_gemm_kernel(
    const unsigned short* __restrict__ yT, const float* __restrict__ proj_w,
    const float* __restrict__ gg, const float* __restrict__ bb,
    const float* __restrict__ mm, const float* __restrict__ vv,
    float* __restrict__ out)
{
  const int n0 = blockIdx.x * 64;
  const int co0 = blockIdx.y * 64;   // 4 tiles
  const int b = blockIdx.z;
  const int t = threadIdx.x;
  __shared__ __align__(16) unsigned short wt[64][136];
  __shared__ __align__(16) unsigned short yt[64][136];
  const int lane = t & 63, wave = t >> 6;
  const int m16 = lane & 15, quad = lane >> 4;

  f32x4 acc[4] = {};
  for (int kc = 0; kc < 2; ++kc) {
    if (kc) __syncthreads();
    {
      const float* wp = proj_w + (size_t)(co0 + (t >> 2)) * 256 + kc * 128 + (t & 3) * 32;
      #pragma unroll
      for (int u = 0; u < 4; ++u) {
        const float4 a0 = *reinterpret_cast<const float4*>(wp + u * 8);
        const float4 a1 = *reinterpret_cast<const float4*>(wp + u * 8 + 4);
        uint4 pw4;
        pw4.x = pk2u(a0.x, a0.y);
        pw4.y = pk2u(a0.z, a0.w);
        pw4.z = pk2u(a1.x, a1.y);
        pw4.w = pk2u(a1.z, a1.w);
        *reinterpret_cast<uint4*>(&wt[t >> 2][(t & 3) * 32 + u * 8]) = pw4;
      }
      const unsigned short* yp = yT + ((size_t)(b * NSP + n0 + (t >> 2))) * 256 + kc * 128 + (t & 3) * 32;
      #pragma unroll
      for (int u = 0; u < 4; ++u)
        *reinterpret_cast<float4*>(&yt[t >> 2][(t & 3) * 32 + u * 8]) =
            *reinterpret_cast<const float4*>(yp + u * 8);
    }
    __syncthreads();
    #pragma unroll
    for (int ks = 0; ks < 4; ++ks) {
      const short8 bf = *reinterpret_cast<const short8*>(&wt[wave * 16 + m16][ks * 32 + quad * 8]);
      #pragma unroll
      for (int nt = 0; nt < 4; ++nt) {
        const short8 af = *reinterpret_cast<const short8*>(&yt[nt * 16 + m16][ks * 32 + quad * 8]);
        acc[nt] = __builtin_amdgcn_mfma_f32_16x16x32_bf16(af, bf, acc[nt], 0, 0, 0);
      }
    }
  }

  const int c = co0 + wave * 16 + m16;
  const float sc = gg[c] * rsqrtf(vv[c] + BEPS);
  const float bi = bb[c] - mm[c] * sc;
  #pragma unroll
  for (int nt = 0; nt < 4; ++nt) {
    const int n = n0 + nt * 16 + quad * 4;
    float4 ov;
    ov.x = acc[nt][0] * sc + bi; ov.y = acc[nt][1] * sc + bi;
    ov.z = acc[nt][2] * sc + bi; ov.w = acc[nt][3] * sc + bi;
    *reinterpret_cast<float4*>(out + ((size_t)(b * 256 + c)) * NSP + n) = ov;
  }
}

extern "C" void kernel_launch(void* const* d_in, const int* in_sizes, int n_in,
                              void* d_out, int out_size, void* d_ws, size_t ws_size,
                              hipStream_t stream)
{
  const float* x      = (const float*)d_in[0];
  const float* qkv_w  = (const float*)d_in[1];
  const float* qkv_g  = (const float*)d_in[2];
  const float* qkv_b  = (const float*)d_in[3];
  const float* qkv_m  = (const float*)d_in[4];
  const float* qkv_v  = (const float*)d_in[5];
  const float* proj_w = (const float*)d_in[6];
  const float* proj_g = (const float*)d_in[7];
  const float* proj_b = (const float*)d_in[8];
  const float* proj_m = (const float*)d_in[9];
  const float* proj_v = (const float*)d_in[10];
  const float* pe_w   = (const float*)d_in[11];
  const float* pe_g   = (const float*)d_in[12];
  const float* pe_b   = (const float*)d_in[13];
  const float* pe_m   = (const float*)d_in[14];
  const float* pe_v   = (const float*)d_in[15];
  float* out = (float*)d_out;

  unsigned short* qb = (unsigned short*)d_ws;             // 2MB (fp16)
  unsigned short* kb = qb + (size_t)8 * NSP * 32;         // 2MB (fp16)
  unsigned short* vb = kb + (size_t)8 * NSP * 32;         // 4MB (bf16)
  unsigned short* Opart = vb + (size_t)8 * 64 * NSP;      // 16MB (bf16)
  float* lpart = (float*)(Opart + (size_t)JSPLIT * 8 * 64 * NSP);  // 512KB
  unsigned short* xT = (unsigned short*)(lpart + (size_t)JSPLIT * 8 * NSP);  // 4MB (fp16)
  unsigned short* yT = xT + (size_t)2 * NSP * 256;        // 4MB (bf16)

  transpose_x_kernel<<<dim3(64, 4, 2), 256, 0, stream>>>(x, xT);
  qkv_gemm_kernel<<<dim3(32, 8, 2), 256, 0, stream>>>(xT, qkv_w, qkv_g, qkv_b, qkv_m, qkv_v,
                                                      qb, kb, vb);
  attn_kernel<<<dim3(32, 8, JSPLIT), 256, 0, stream>>>(qb, kb, vb, Opart, lpart);
  fuse_kernel<<<dim3(64, 8), 256, 0, stream>>>(Opart, lpart, vb,
                                               pe_w, pe_g, pe_b, pe_m, pe_v, yT);
  proj_gemm_kernel<<<dim3(64, 4, 2), 256, 0, stream>>>(yT, proj_w, proj_g, proj_b, proj_m, proj_v,
                                                       out);
}

// Round 10
// 149.035 us; speedup vs baseline: 1.0932x; 1.0374x over previous
//
#include <hip/hip_runtime.h>
#include <hip/hip_bf16.h>

#define NSP 4096
#define BEPS 1e-5f
#define JSPLIT 4
#define JCHUNK (NSP / JSPLIT)

using short8  = __attribute__((ext_vector_type(8))) short;
using half8   = __attribute__((ext_vector_type(8))) _Float16;
using f32x4   = __attribute__((ext_vector_type(4))) float;
using f32x16  = __attribute__((ext_vector_type(16))) float;

// scale * log2(e) : softmax exp(s*scale) == exp2(s*SCALE_LOG2E)
// log2(e)/sqrt(32) = 1.4426950408889634 / 5.656854249492381
#define SCALE_LOG2E 0.2550348883f

__device__ __forceinline__ float b2f(unsigned short u) {
  return __uint_as_float(((unsigned)u) << 16);
}
__device__ __forceinline__ float b2f_lo(unsigned w) {
  return __uint_as_float(w << 16);
}
__device__ __forceinline__ float b2f_hi(unsigned w) {
  return __uint_as_float(w & 0xffff0000u);
}
// float -> bf16 bits, round-nearest-even (manual; non-hot paths)
__device__ __forceinline__ unsigned short f2b(float x) {
  unsigned u = __float_as_uint(x);
  u += 0x7fffu + ((u >> 16) & 1u);
  return (unsigned short)(u >> 16);
}
__device__ __forceinline__ unsigned pk_bf16(float a, float b) {
  return ((unsigned)f2b(b) << 16) | (unsigned)f2b(a);
}
// HW packed convert: v_cvt_pk_bf16_f32 on gfx950 (1 inst vs ~10 manual)
__device__ __forceinline__ unsigned pk2u(float a, float b) {
  __hip_bfloat162 h = __float22bfloat162_rn(float2{a, b});
  unsigned r;
  __builtin_memcpy(&r, &h, sizeof(r));
  return r;
}
// float -> fp16 bits (RNE via v_cvt_f16_f32)
__device__ __forceinline__ unsigned short f2h(float x) {
  _Float16 h = (_Float16)x;
  unsigned short u;
  __builtin_memcpy(&u, &h, sizeof(u));
  return u;
}
__device__ __forceinline__ unsigned pk_h2(float a, float b) {
  return ((unsigned)f2h(b) << 16) | (unsigned)f2h(a);
}

// ---------------- Kernel 0: transpose-cast x -> xT (b, n, c) fp16; z==2 casts weights --
// (r4-exact: r9's fold-cast-into-GEMM regressed — doubled bytes + cvt VALU in the
// serial staging phase of 8-waves/CU kernels with no latency-hiding headroom.)
__global__ __launch_bounds__(256) void transpose_x_kernel(
    const float* __restrict__ x, unsigned short* __restrict__ xT,
    const float* __restrict__ qkv_w, const float* __restrict__ proj_w,
    unsigned short* __restrict__ wqb, unsigned short* __restrict__ wpb)
{
  const int t = threadIdx.x;
  if (blockIdx.z == 2) {   // weight cast lane: 256 blocks x 256 thr, 3 elems each
    const int tid = (blockIdx.x * 4 + blockIdx.y) * 256 + t;   // 0..65535
    #pragma unroll
    for (int u = 0; u < 3; ++u) {
      const int i = tid + u * 65536;
      if (i < 131072)  wqb[i] = f2h(qkv_w[i]);
      else             wpb[i - 131072] = f2b(proj_w[i - 131072]);
    }
    return;
  }
  const int n0 = blockIdx.x * 64, c0 = blockIdx.y * 64, b = blockIdx.z;
  __shared__ __align__(16) unsigned short tx[64][72];   // [n][c]
  const int row = t >> 2;        // c index within tile
  const int seg = t & 3;         // 16 n each
  {
    const float* xp = x + ((size_t)(b * 256 + c0 + row)) * NSP + n0 + seg * 16;
    #pragma unroll
    for (int q4 = 0; q4 < 4; ++q4) {
      const float4 a = *reinterpret_cast<const float4*>(xp + q4 * 4);
      tx[seg * 16 + q4 * 4 + 0][row] = f2h(a.x);
      tx[seg * 16 + q4 * 4 + 1][row] = f2h(a.y);
      tx[seg * 16 + q4 * 4 + 2][row] = f2h(a.z);
      tx[seg * 16 + q4 * 4 + 3][row] = f2h(a.w);
    }
  }
  __syncthreads();
  const int nrow = t >> 2, ch = t & 3;
  unsigned short* op = xT + ((size_t)(b * NSP + n0 + nrow)) * 256 + c0 + ch * 16;
  *reinterpret_cast<float4*>(op)     = *reinterpret_cast<const float4*>(&tx[nrow][ch * 16]);
  *reinterpret_cast<float4*>(op + 8) = *reinterpret_cast<const float4*>(&tx[nrow][ch * 16 + 8]);
}

// ---------------- Kernel 1: MFMA qkv GEMM (fp16) + BN + scatter (64-n tiles) -----------
// n-tile 128 -> 64 (r9 finding: grid 512 = 2 blocks/CU = 8 waves/CU was the binding
// constraint on this latency-bound kernel). Grid (64,8,2) = 1024 blocks = 4 blocks/CU
// = 16 waves/CU; LDS 52 -> 35 KB; acc 32 -> 16 AGPRs; per-block staging halves.
// Weight restaging redundancy doubles but is L2-resident (~32 MB aggregate ≈ 1 us).
__global__ __launch_bounds__(256) void qkv_gemm_kernel(
    const unsigned short* __restrict__ xT, const unsigned short* __restrict__ wqb,
    const float* __restrict__ gg, const float* __restrict__ bb,
    const float* __restrict__ mm, const float* __restrict__ vv,
    unsigned short* __restrict__ qb, unsigned short* __restrict__ kb,
    unsigned short* __restrict__ vb)
{
  const int n0 = blockIdx.x * 64;
  const int cotile = blockIdx.y;           // 8 tiles of 64 co
  const int b = blockIdx.z;
  const int co0 = cotile * 64;
  const int t = threadIdx.x;
  __shared__ __align__(16) unsigned short wt[64][136];    // [co][k-chunk 128] fp16
  __shared__ __align__(16) unsigned short xt[64][136];    // [n][k-chunk 128] fp16
  const int lane = t & 63, wave = t >> 6;
  const int m16 = lane & 15, quad = lane >> 4;

  f32x4 acc[4] = {};
  for (int kc = 0; kc < 2; ++kc) {
    if (kc) __syncthreads();
    {
      const unsigned short* wp = wqb + (size_t)(co0 + (t >> 2)) * 256 + kc * 128 + (t & 3) * 32;
      #pragma unroll
      for (int u = 0; u < 4; ++u)
        *reinterpret_cast<float4*>(&wt[t >> 2][(t & 3) * 32 + u * 8]) =
            *reinterpret_cast<const float4*>(wp + u * 8);
      const unsigned short* xp = xT + ((size_t)(b * NSP + n0 + (t >> 2))) * 256 + kc * 128 + (t & 3) * 32;
      #pragma unroll
      for (int u = 0; u < 4; ++u)
        *reinterpret_cast<float4*>(&xt[t >> 2][(t & 3) * 32 + u * 8]) =
            *reinterpret_cast<const float4*>(xp + u * 8);
    }
    __syncthreads();
    if ((cotile & 1) == 0) {   // q/k: A = W (m=co), B = X (n=spatial)
      #pragma unroll
      for (int ks = 0; ks < 4; ++ks) {
        const half8 af = *reinterpret_cast<const half8*>(&wt[wave * 16 + m16][ks * 32 + quad * 8]);
        #pragma unroll
        for (int nt = 0; nt < 4; ++nt) {
          const half8 bf = *reinterpret_cast<const half8*>(&xt[nt * 16 + m16][ks * 32 + quad * 8]);
          acc[nt] = __builtin_amdgcn_mfma_f32_16x16x32_f16(af, bf, acc[nt], 0, 0, 0);
        }
      }
    } else {                   // v: swapped -> A = X (m=spatial), B = W (n=co)
      #pragma unroll
      for (int ks = 0; ks < 4; ++ks) {
        const half8 bf = *reinterpret_cast<const half8*>(&wt[wave * 16 + m16][ks * 32 + quad * 8]);
        #pragma unroll
        for (int nt = 0; nt < 4; ++nt) {
          const half8 af = *reinterpret_cast<const half8*>(&xt[nt * 16 + m16][ks * 32 + quad * 8]);
          acc[nt] = __builtin_amdgcn_mfma_f32_16x16x32_f16(af, bf, acc[nt], 0, 0, 0);
        }
      }
    }
  }

  const int head = cotile >> 1;
  const int bh = b * 4 + head;
  if ((cotile & 1) == 0) {
    const int coh = wave * 16 + quad * 4;   // 0..63 within head half (q if <32 else k)
    const bool isq = (coh < 32);
    const float fold = isq ? SCALE_LOG2E : 1.0f;   // pre-scale q for softmax exp2
    float sc[4], bi[4];
    #pragma unroll
    for (int r = 0; r < 4; ++r) {
      const int c = co0 + coh + r;
      const float s0 = gg[c] * rsqrtf(vv[c] + BEPS);
      sc[r] = s0 * fold;
      bi[r] = (bb[c] - mm[c] * s0) * fold;
    }
    unsigned short* dst = isq ? qb : kb;
    const int d0 = coh & 31;
    #pragma unroll
    for (int nt = 0; nt < 4; ++nt) {
      const int i = n0 + nt * 16 + m16;
      uint2 pk2;
      pk2.x = pk_h2(acc[nt][0] * sc[0] + bi[0], acc[nt][1] * sc[1] + bi[1]);
      pk2.y = pk_h2(acc[nt][2] * sc[2] + bi[2], acc[nt][3] * sc[3] + bi[3]);
      *reinterpret_cast<uint2*>(dst + ((size_t)bh * NSP + i) * 32 + d0) = pk2;
    }
  } else {
    const int c = co0 + wave * 16 + m16;
    const float sc = gg[c] * rsqrtf(vv[c] + BEPS);
    const float bi = bb[c] - mm[c] * sc;
    const int d = wave * 16 + m16;
    #pragma unroll
    for (int nt = 0; nt < 4; ++nt) {
      const int j = n0 + nt * 16 + quad * 4;
      uint2 pk2;
      pk2.x = pk_bf16(acc[nt][0] * sc + bi, acc[nt][1] * sc + bi);
      pk2.y = pk_bf16(acc[nt][2] * sc + bi, acc[nt][3] * sc + bi);
      *reinterpret_cast<uint2*>(vb + ((size_t)(bh * 64 + d)) * NSP + j) = pk2;
    }
  }
}

// ---------------- Kernel 2: MFMA flash attention, 32x32 MFMA, exchange-free PV ---------
// (r4-verified structure: single K/V buffer, 2 barriers/tile, (256,4).)
// Q pre-scaled by scale*log2e (qkv epilogue) -> softmax is exp2(s) directly.
// 32x32x16 S-MFMA (A=K m=j, B=Q n=i): lane holds P[i=lane&31][j = (r&3)+8*(r>>2)+4*hi].
// EXCHANGE-FREE PV: A-frag = lane's own pk words; V j-columns pre-permuted in LDS
// (q0,q2,q1,q3 within each 16-j block) so Σ_j P[j]V[j] is unchanged.
// REG BUDGET (r3+r8 lessons): true unified footprint ~112 regs (64 VGPR + ~48 AGPR
// incl. sacc). (256,4) = 128 budget: fits, no spill — the minimum viable bound.
// (256,5) = 102: compiler squeezed to 48 VGPR + scratch spills. DO NOT raise waves/EU.
__global__ __launch_bounds__(256, 4) void attn_kernel(
    const unsigned short* __restrict__ qb, const unsigned short* __restrict__ kb,
    const unsigned short* __restrict__ vb,
    unsigned short* __restrict__ Opart, float* __restrict__ lpart)
{
  const int i0    = blockIdx.x * 128;
  const int bh    = blockIdx.y;
  const int split = blockIdx.z;
  const int jbase = split * JCHUNK;
  const int t  = threadIdx.x;
  const int lane = t & 63, wave = t >> 6;
  const int l31 = lane & 31, hi = lane >> 5;

  // 14336 B total; qs (10240 B) overlays ks+vs (5120 + 9216 B)
  __shared__ __align__(16) unsigned short smem[7168];
  unsigned short (*qs)[40] = (unsigned short(*)[40])smem;          // [i][d] fp16
  unsigned short (*ks)[40] = (unsigned short(*)[40])smem;          // [j][d] fp16
  unsigned short (*vs)[72] = (unsigned short(*)[72])(smem + 2560); // [d][j-permuted] bf16

  {  // stage Q once: 128 rows x 32 fp16 (each thread 32B)
    const unsigned short* qp = qb + ((size_t)bh * NSP + i0) * 32;
    const int r = t >> 1, h = t & 1;
    *reinterpret_cast<float4*>(&qs[r][h * 16]) =
        *reinterpret_cast<const float4*>(qp + r * 32 + h * 16);
    *reinterpret_cast<float4*>(&qs[r][h * 16 + 8]) =
        *reinterpret_cast<const float4*>(qp + r * 32 + h * 16 + 8);
  }

  const int srow = t >> 2, schunk = t & 3;
  const unsigned short* kbase = kb + (size_t)bh * NSP * 32;
  const unsigned short* vbase = vb + (size_t)bh * 64 * NSP;

  // prologue: tile 0 -> regs (overlaps Q staging latency)
  float4 kreg, vreg0, vreg1;
  kreg  = *reinterpret_cast<const float4*>(kbase + (size_t)(jbase + srow) * 32 + schunk * 8);
  vreg0 = *reinterpret_cast<const float4*>(vbase + (size_t)srow * NSP + jbase + schunk * 16);
  vreg1 = *reinterpret_cast<const float4*>(vbase + (size_t)srow * NSP + jbase + schunk * 16 + 8);

  __syncthreads();   // Q visible
  // Q B-frags: B[k=d][col=i]: lane reads Q[wave*32 + l31][kt*16 + hi*8 ..+7]
  half8 qfrag[2];
  qfrag[0] = *reinterpret_cast<const half8*>(&qs[wave * 32 + l31][hi * 8]);
  qfrag[1] = *reinterpret_cast<const half8*>(&qs[wave * 32 + l31][16 + hi * 8]);
  __syncthreads();   // all qfrag reads done before ks/vs overwrite qs

  // commit tile 0 to LDS; V columns quad-permuted (q0,q2,q1,q3 within each 16-j block)
  *reinterpret_cast<float4*>(&ks[srow][schunk * 8]) = kreg;
  {
    uint2* vd = reinterpret_cast<uint2*>(&vs[srow][schunk * 16]);
    const uint2* v0 = reinterpret_cast<const uint2*>(&vreg0);
    const uint2* v1 = reinterpret_cast<const uint2*>(&vreg1);
    vd[0] = v0[0];   // pos 0-3  <- j 0-3   (q0)
    vd[1] = v1[0];   // pos 4-7  <- j 8-11  (q2)
    vd[2] = v0[1];   // pos 8-11 <- j 4-7   (q1)
    vd[3] = v1[1];   // pos12-15 <- j 12-15 (q3)
  }
  __syncthreads();   // tile 0 visible

  float rsum = 0.f;
  f32x16 oacc[2] = {};   // [dt] : O[i-runs][d = dt*32 + l31]

  for (int jt0 = 0; jt0 < JCHUNK; jt0 += 64) {
    const bool more = (jt0 + 64) < JCHUNK;
    if (more) {   // prefetch tile j+1 into regs; latency overlaps compute below
      const int jn = jbase + jt0 + 64;
      kreg  = *reinterpret_cast<const float4*>(kbase + (size_t)(jn + srow) * 32 + schunk * 8);
      vreg0 = *reinterpret_cast<const float4*>(vbase + (size_t)srow * NSP + jn + schunk * 16);
      vreg1 = *reinterpret_cast<const float4*>(vbase + (size_t)srow * NSP + jn + schunk * 16 + 8);
    }

    // K A-frags: A[row=j][k=d]: lane reads K[jt32*32 + l31][kt*16 + hi*8 ..+7]
    half8 kf[2][2];
    #pragma unroll
    for (int jt32 = 0; jt32 < 2; ++jt32) {
      kf[jt32][0] = *reinterpret_cast<const half8*>(&ks[jt32 * 32 + l31][hi * 8]);
      kf[jt32][1] = *reinterpret_cast<const half8*>(&ks[jt32 * 32 + l31][16 + hi * 8]);
    }

    #pragma unroll
    for (int jt32 = 0; jt32 < 2; ++jt32) {
      // S tile: C[row=j][col=i], j = (r&3)+8*(r>>2)+4*hi + jt32*32, i = l31 (+wave*32)
      f32x16 sacc = {};
      sacc = __builtin_amdgcn_mfma_f32_32x32x16_f16(kf[jt32][0], qfrag[0], sacc, 0, 0, 0);
      sacc = __builtin_amdgcn_mfma_f32_32x32x16_f16(kf[jt32][1], qfrag[1], sacc, 0, 0, 0);

      // softmax numerator: exp2 (q pre-scaled), accumulate row-sum, pack to bf16 pairs
      unsigned pk[8];
      #pragma unroll
      for (int c = 0; c < 8; ++c) {
        const float p0 = __builtin_amdgcn_exp2f(sacc[2 * c]);
        const float p1 = __builtin_amdgcn_exp2f(sacc[2 * c + 1]);
        rsum += p0 + p1;
        pk[c] = pk2u(p0, p1);   // pair (j, j+1) within a 4-run
      }

      // PV: A-frag = own pk words (no cross-lane exchange; V columns pre-permuted).
      #pragma unroll
      for (int kt = 0; kt < 2; ++kt) {
        uint4 aw;
        aw.x = pk[4 * kt + 0];
        aw.y = pk[4 * kt + 1];
        aw.z = pk[4 * kt + 2];
        aw.w = pk[4 * kt + 3];
        short8 af;
        __builtin_memcpy(&af, &aw, 16);
        #pragma unroll
        for (int dt = 0; dt < 2; ++dt) {
          const short8 vf = *reinterpret_cast<const short8*>(
              &vs[dt * 32 + l31][jt32 * 32 + kt * 16 + hi * 8]);
          oacc[dt] = __builtin_amdgcn_mfma_f32_32x32x16_bf16(af, vf, oacc[dt], 0, 0, 0);
        }
      }
    }

    if (more) {   // commit prefetched tile to LDS
      __syncthreads();   // all reads of ks/vs for tile j done
      *reinterpret_cast<float4*>(&ks[srow][schunk * 8]) = kreg;
      uint2* vd = reinterpret_cast<uint2*>(&vs[srow][schunk * 16]);
      const uint2* v0 = reinterpret_cast<const uint2*>(&vreg0);
      const uint2* v1 = reinterpret_cast<const uint2*>(&vreg1);
      vd[0] = v0[0];
      vd[1] = v1[0];
      vd[2] = v0[1];
      vd[3] = v1[1];
      __syncthreads();   // tile j+1 visible
    }
  }

  // finalize l for this block's j-range: lane and lane^32 hold complementary j-subsets
  {
    float rs = rsum;
    rs += __shfl_xor(rs, 32);
    if (hi == 0)
      lpart[((size_t)split * 8 + bh) * NSP + i0 + wave * 32 + l31] = rs;
  }

  // store unnormalized O partial as bf16: [split][bh][d][i]
  // reg r -> i = (r&3) + 8*(r>>2) + 4*hi  (runs of 4, pack pairs -> uint2 per run)
  #pragma unroll
  for (int dt = 0; dt < 2; ++dt) {
    const int d = dt * 32 + l31;
    #pragma unroll
    for (int R = 0; R < 4; ++R) {
      uint2 pk2;
      pk2.x = pk2u(oacc[dt][4 * R + 0], oacc[dt][4 * R + 1]);
      pk2.y = pk2u(oacc[dt][4 * R + 2], oacc[dt][4 * R + 3]);
      *reinterpret_cast<uint2*>(Opart +
          (((size_t)split * 8 + bh) * 64 + d) * NSP + i0 + wave * 32 + 8 * R + 4 * hi) = pk2;
    }
  }
}

// ---------------- Kernel 3: fused combine + pe -> yT (b, n, c) bf16 (r4-exact) ---------
__global__ __launch_bounds__(256) void fuse_kernel(
    const unsigned short* __restrict__ Opart, const float* __restrict__ lpart,
    const unsigned short* __restrict__ vb,
    const float* __restrict__ pw, const float* __restrict__ pg,
    const float* __restrict__ pb, const float* __restrict__ pm,
    const float* __restrict__ pv,
    unsigned short* __restrict__ yT)
{
  const int py = blockIdx.x;       // spatial row
  const int bh = blockIdx.y;       // 8
  const int b = bh >> 2, h = bh & 3;
  const int t = threadIdx.x;
  const int d = t >> 2, seg = t & 3;      // d 0..63 ; px window = seg*16..+15
  __shared__ float lsum[64];              // stores RECIPROCAL of row-sum
  __shared__ __align__(16) unsigned short yt[64][72];   // [px][d]

  if (t < 64) {
    float ls = 0.f;
    #pragma unroll
    for (int s = 0; s < JSPLIT; ++s)
      ls += lpart[((size_t)s * 8 + bh) * NSP + py * 64 + t];
    lsum[t] = 1.0f / ls;
  }
  __syncthreads();

  const int c = h * 64 + d;
  const int i0 = py * 64 + seg * 16;
  float os[16] = {};
  #pragma unroll
  for (int s = 0; s < JSPLIT; ++s) {
    const uint4* op = reinterpret_cast<const uint4*>(
        Opart + (((size_t)s * 8 + bh) * 64 + d) * NSP + i0);
    const uint4 a = op[0], e = op[1];
    os[0]  += b2f_lo(a.x); os[1]  += b2f_hi(a.x);
    os[2]  += b2f_lo(a.y); os[3]  += b2f_hi(a.y);
    os[4]  += b2f_lo(a.z); os[5]  += b2f_hi(a.z);
    os[6]  += b2f_lo(a.w); os[7]  += b2f_hi(a.w);
    os[8]  += b2f_lo(e.x); os[9]  += b2f_hi(e.x);
    os[10] += b2f_lo(e.y); os[11] += b2f_hi(e.y);
    os[12] += b2f_lo(e.z); os[13] += b2f_hi(e.z);
    os[14] += b2f_lo(e.w); os[15] += b2f_hi(e.w);
  }

  float w9[9];
  #pragma unroll
  for (int i = 0; i < 9; ++i) w9[i] = pw[c * 9 + i];
  const float sc = pg[c] * rsqrtf(pv[c] + BEPS);
  const float bi = pb[c] - pm[c] * sc;
  const unsigned short* vrow = vb + ((size_t)(bh * 64 + d)) * NSP;

  float conv[16] = {};
  #pragma unroll
  for (int dy = -1; dy <= 1; ++dy) {
    const int yy = py + dy;
    if (yy < 0 || yy > 63) continue;
    const unsigned short* vr = vrow + yy * 64 + seg * 16;
    float vals[18];
    const uint4 m0 = *reinterpret_cast<const uint4*>(vr);
    const uint4 m1 = *reinterpret_cast<const uint4*>(vr + 8);
    vals[1]  = b2f_lo(m0.x); vals[2]  = b2f_hi(m0.x);
    vals[3]  = b2f_lo(m0.y); vals[4]  = b2f_hi(m0.y);
    vals[5]  = b2f_lo(m0.z); vals[6]  = b2f_hi(m0.z);
    vals[7]  = b2f_lo(m0.w); vals[8]  = b2f_hi(m0.w);
    vals[9]  = b2f_lo(m1.x); vals[10] = b2f_hi(m1.x);
    vals[11] = b2f_lo(m1.y); vals[12] = b2f_hi(m1.y);
    vals[13] = b2f_lo(m1.z); vals[14] = b2f_hi(m1.z);
    vals[15] = b2f_lo(m1.w); vals[16] = b2f_hi(m1.w);
    vals[0]  = (seg > 0) ? b2f_hi(*reinterpret_cast<const unsigned*>(vr - 2)) : 0.f;
    vals[17] = (seg < 3) ? b2f_lo(*reinterpret_cast<const unsigned*>(vr + 16)) : 0.f;
    const float wr0 = w9[(dy + 1) * 3 + 0], wr1 = w9[(dy + 1) * 3 + 1], wr2 = w9[(dy + 1) * 3 + 2];
    #pragma unroll
    for (int u = 0; u < 16; ++u)
      conv[u] += vals[u] * wr0 + vals[u + 1] * wr1 + vals[u + 2] * wr2;
  }

  #pragma unroll
  for (int u = 0; u < 16; ++u) {
    const float yv = os[u] * lsum[seg * 16 + u] + conv[u] * sc + bi;
    yt[seg * 16 + u][d] = f2b(yv);
  }
  __syncthreads();

  const int prow = t >> 2, ch = t & 3;
  unsigned short* op = yT + ((size_t)(b * NSP + py * 64 + prow)) * 256 + h * 64 + ch * 16;
  *reinterpret_cast<float4*>(op)     = *reinterpret_cast<const float4*>(&yt[prow][ch * 16]);
  *reinterpret_cast<float4*>(op + 8) = *reinterpret_cast<const float4*>(&yt[prow][ch * 16 + 8]);
}

// ---------------- Kernel 4: MFMA proj GEMM + BN -> out f32 (32-n tiles) -----------------
// n-tile 64 -> 32: grid (128,4,2) = 1024 blocks = 4 blocks/CU = 16 waves/CU (was 8).
// LDS 35 -> 26 KB; acc 16 -> 8 AGPRs. Same occupancy rationale as qkv.
__global__ __launch_bounds__(256) void proj_gemm_kernel(
    const unsigned short* __restrict__ yT, const unsigned short* __restrict__ wpb,
    const float* __restrict__ gg, const float* __restrict__ bb,
    const float* __restrict__ mm, const float* __restrict__ vv,
    float* __restrict__ out)
{
  const int n0 = blockIdx.x * 32;
  const int co0 = blockIdx.y * 64;   // 4 tiles
  const int b = blockIdx.z;
  const int t = threadIdx.x;
  __shared__ __align__(16) unsigned short wt[64][136];
  __shared__ __align__(16) unsigned short yt[32][136];
  const int lane = t & 63, wave = t >> 6;
  const int m16 = lane & 15, quad = lane >> 4;

  f32x4 acc[2] = {};
  for (int kc = 0; kc < 2; ++kc) {
    if (kc) __syncthreads();
    {
      const unsigned short* wp = wpb + (size_t)(co0 + (t >> 2)) * 256 + kc * 128 + (t & 3) * 32;
      #pragma unroll
      for (int u = 0; u < 4; ++u)
        *reinterpret_cast<float4*>(&wt[t >> 2][(t & 3) * 32 + u * 8]) =
            *reinterpret_cast<const float4*>(wp + u * 8);
      const unsigned short* yp = yT + ((size_t)(b * NSP + n0 + (t >> 3))) * 256 + kc * 128 + (t & 7) * 16;
      #pragma unroll
      for (int u = 0; u < 2; ++u)
        *reinterpret_cast<float4*>(&yt[t >> 3][(t & 7) * 16 + u * 8]) =
            *reinterpret_cast<const float4*>(yp + u * 8);
    }
    __syncthreads();
    #pragma unroll
    for (int ks = 0; ks < 4; ++ks) {
      const short8 bf = *reinterpret_cast<const short8*>(&wt[wave * 16 + m16][ks * 32 + quad * 8]);
      #pragma unroll
      for (int nt = 0; nt < 2; ++nt) {
        const short8 af = *reinterpret_cast<const short8*>(&yt[nt * 16 + m16][ks * 32 + quad * 8]);
        acc[nt] = __builtin_amdgcn_mfma_f32_16x16x32_bf16(af, bf, acc[nt], 0, 0, 0);
      }
    }
  }

  const int c = co0 + wave * 16 + m16;
  const float sc = gg[c] * rsqrtf(vv[c] + BEPS);
  const float bi = bb[c] - mm[c] * sc;
  #pragma unroll
  for (int nt = 0; nt < 2; ++nt) {
    const int n = n0 + nt * 16 + quad * 4;
    float4 ov;
    ov.x = acc[nt][0] * sc + bi; ov.y = acc[nt][1] * sc + bi;
    ov.z = acc[nt][2] * sc + bi; ov.w = acc[nt][3] * sc + bi;
    *reinterpret_cast<float4*>(out + ((size_t)(b * 256 + c)) * NSP + n) = ov;
  }
}

extern "C" void kernel_launch(void* const* d_in, const int* in_sizes, int n_in,
                              void* d_out, int out_size, void* d_ws, size_t ws_size,
                              hipStream_t stream)
{
  const float* x      = (const float*)d_in[0];
  const float* qkv_w  = (const float*)d_in[1];
  const float* qkv_g  = (const float*)d_in[2];
  const float* qkv_b  = (const float*)d_in[3];
  const float* qkv_m  = (const float*)d_in[4];
  const float* qkv_v  = (const float*)d_in[5];
  const float* proj_w = (const float*)d_in[6];
  const float* proj_g = (const float*)d_in[7];
  const float* proj_b = (const float*)d_in[8];
  const float* proj_m = (const float*)d_in[9];
  const float* proj_v = (const float*)d_in[10];
  const float* pe_w   = (const float*)d_in[11];
  const float* pe_g   = (const float*)d_in[12];
  const float* pe_b   = (const float*)d_in[13];
  const float* pe_m   = (const float*)d_in[14];
  const float* pe_v   = (const float*)d_in[15];
  float* out = (float*)d_out;

  unsigned short* qb = (unsigned short*)d_ws;             // 2MB (fp16)
  unsigned short* kb = qb + (size_t)8 * NSP * 32;         // 2MB (fp16)
  unsigned short* vb = kb + (size_t)8 * NSP * 32;         // 4MB (bf16)
  unsigned short* Opart = vb + (size_t)8 * 64 * NSP;      // 16MB (bf16)
  float* lpart = (float*)(Opart + (size_t)JSPLIT * 8 * 64 * NSP);  // 512KB
  unsigned short* xT = (unsigned short*)(lpart + (size_t)JSPLIT * 8 * NSP);  // 4MB (fp16)
  unsigned short* yT = xT + (size_t)2 * NSP * 256;        // 4MB (bf16)
  unsigned short* wqb = yT + (size_t)2 * NSP * 256;       // 256KB (fp16)
  unsigned short* wpb = wqb + (size_t)512 * 256;          // 128KB (bf16)

  transpose_x_kernel<<<dim3(64, 4, 3), 256, 0, stream>>>(x, xT, qkv_w, proj_w, wqb, wpb);
  qkv_gemm_kernel<<<dim3(64, 8, 2), 256, 0, stream>>>(xT, wqb, qkv_g, qkv_b, qkv_m, qkv_v,
                                                      qb, kb, vb);
  attn_kernel<<<dim3(32, 8, JSPLIT), 256, 0, stream>>>(qb, kb, vb, Opart, lpart);
  fuse_kernel<<<dim3(64, 8), 256, 0, stream>>>(Opart, lpart, vb,
                                               pe_w, pe_g, pe_b, pe_m, pe_v, yT);
  proj_gemm_kernel<<<dim3(128, 4, 2), 256, 0, stream>>>(yT, wpb, proj_g, proj_b, proj_m, proj_v,
                                                        out);
}